// Round 3
// baseline (201.440 us; speedup 1.0000x reference)
//
#include <hip/hip_runtime.h>
#include <stdint.h>

#define NROWS 8192
#define DDIM 512
#define NCLS 16
#define T2INV 20.0f
#define EPSV 1e-5f
#define NTILE 64                          // NROWS / 128
#define NTRI (NTILE * (NTILE + 1) / 2)    // 2080 upper-tri tiles
#define NBLK (NTRI * 2)                   // 4160 (both matrices)

typedef __bf16 bf16x8 __attribute__((ext_vector_type(8)));
typedef short short8 __attribute__((ext_vector_type(8)));
typedef float f32x4 __attribute__((ext_vector_type(4)));

__device__ __forceinline__ ushort f2bf(float f) {
  uint32_t b = __float_as_uint(f);
  b += 0x7FFF + ((b >> 16) & 1);  // round-to-nearest-even
  return (ushort)(b >> 16);
}

// async global->LDS, 16B per lane; lds must be wave-uniform base, g per-lane.
__device__ __forceinline__ void async16(void* lds, const void* g) {
  auto gp = (__attribute__((address_space(1))) uint32_t*)(uintptr_t)g;
  auto lp = (__attribute__((address_space(3))) uint32_t*)(uintptr_t)lds;
  __builtin_amdgcn_global_load_lds(gp, lp, 16, 0, 0);
}

// Row-normalize both matrices, emit bf16, one wave per row.
__global__ __launch_bounds__(256) void norm_kernel(const float* __restrict__ text,
                                                   const float* __restrict__ image,
                                                   ushort* __restrict__ out) {
  const int w = threadIdx.x >> 6, l = threadIdx.x & 63;
  const int rid = blockIdx.x * 4 + w;            // 0 .. 2*NROWS-1
  const int m = rid >> 13;
  const int row = rid & (NROWS - 1);
  const float* src = (m ? image : text) + (size_t)row * DDIM;
  float4 v0 = ((const float4*)src)[l];
  float4 v1 = ((const float4*)src)[64 + l];
  float s = v0.x * v0.x + v0.y * v0.y + v0.z * v0.z + v0.w * v0.w +
            v1.x * v1.x + v1.y * v1.y + v1.z * v1.z + v1.w * v1.w;
  #pragma unroll
  for (int off = 32; off; off >>= 1) s += __shfl_xor(s, off);
  const float inv = 1.0f / fmaxf(sqrtf(s), 1e-12f);
  ushort4 o0, o1;
  o0.x = f2bf(v0.x * inv); o0.y = f2bf(v0.y * inv);
  o0.z = f2bf(v0.z * inv); o0.w = f2bf(v0.w * inv);
  o1.x = f2bf(v1.x * inv); o1.y = f2bf(v1.y * inv);
  o1.z = f2bf(v1.z * inv); o1.w = f2bf(v1.w * inv);
  ushort* drow = out + (size_t)rid * DDIM;
  ((ushort4*)drow)[l] = o0;
  ((ushort4*)drow)[64 + l] = o1;
}

// 128x128 bf16 MFMA Gram tile over the upper triangle (bi<=bj).
// Double-buffered LDS, BK=64, ONE barrier per K-step (prefetch overlaps the
// vmcnt(0) drain with compute). Fused exp + class-weighted row+col epilogue.
// LDS per 16-row chunk: 16B-slot (row, s) holds global k-slot s ^ ((row>>1)&3)
// — swizzle on the GLOBAL source (global_load_lds writes linearly) and the
// same XOR on the ds_read address.
__global__ __launch_bounds__(256) void gram_kernel(const ushort* __restrict__ Fall,
                                                   const int* __restrict__ label,
                                                   float* __restrict__ denAll) {
  // XCD-chunked bijective swizzle: 4160 % 8 == 0, chunk = 520 per XCD.
  const int bid = blockIdx.x;
  const int bs = (bid & 7) * (NBLK / 8) + (bid >> 3);
  const int mat = bs >= NTRI;
  const int t = mat ? bs - NTRI : bs;
  const ushort* F = Fall + (size_t)mat * NROWS * DDIM;
  float* den = denAll + (size_t)mat * NROWS;

  // decode triangular tile id -> (q=row tile, p=col tile), q <= p
  int p = (int)((sqrtf(8.0f * (float)t + 1.0f) - 1.0f) * 0.5f);
  while ((p + 1) * (p + 2) / 2 <= t) ++p;
  while (p * (p + 1) / 2 > t) --p;
  const int q = t - p * (p + 1) / 2;
  const int row0 = q * 128, col0 = p * 128;
  const bool diagTile = (q == p);

  const int w = threadIdx.x >> 6, l = threadIdx.x & 63;
  const int wr = w >> 1, wc = w & 1;

  // [buf][khalf][chunk*512 + lane*8]
  __shared__ ushort Alds[2][2][128 * 32];
  __shared__ ushort Blds[2][2][128 * 32];

  f32x4 acc[4][4] = {};

  const int lr = l >> 2;                                    // row within chunk
  const int lk = (((l & 3) ^ ((l >> 3) & 3)) * 8);          // swizzled fetch slot
  const int rdk = (((l >> 4) ^ (((l & 15) >> 1) & 3)) * 8); // swizzled read slot

  const ushort* gA = F + (size_t)row0 * DDIM + lk;
  const ushort* gB = F + (size_t)col0 * DDIM + lk;

  // stage one BK=64 tile into buffer `buf` from k-offset k0
  #define STAGE(buf, k0)                                                     \
    {                                                                        \
      _Pragma("unroll")                                                      \
      for (int h = 0; h < 2; ++h) {                                          \
        _Pragma("unroll")                                                    \
        for (int c = 0; c < 2; ++c) {                                        \
          const int chunk = w * 2 + c;                                       \
          const int r = chunk * 16 + lr;                                     \
          async16(&Alds[buf][h][chunk * 512], gA + (size_t)r * DDIM + (k0) + h * 32); \
          async16(&Blds[buf][h][chunk * 512], gB + (size_t)r * DDIM + (k0) + h * 32); \
        }                                                                    \
      }                                                                      \
    }

  STAGE(0, 0);
  __syncthreads();

  int cur = 0;
  for (int t64 = 0; t64 < DDIM / 64; ++t64) {
    if (t64 < DDIM / 64 - 1) STAGE(cur ^ 1, (t64 + 1) * 64);
    #pragma unroll
    for (int h = 0; h < 2; ++h) {
      short8 a[4], b[4];
      #pragma unroll
      for (int f = 0; f < 4; ++f) {
        a[f] = *(const short8*)&Alds[cur][h][(wr * 64 + f * 16 + (l & 15)) * 32 + rdk];
        b[f] = *(const short8*)&Blds[cur][h][(wc * 64 + f * 16 + (l & 15)) * 32 + rdk];
      }
      #pragma unroll
      for (int i = 0; i < 4; ++i)
        #pragma unroll
        for (int j = 0; j < 4; ++j)
          acc[i][j] = __builtin_amdgcn_mfma_f32_16x16x32_bf16(
              __builtin_bit_cast(bf16x8, a[i]), __builtin_bit_cast(bf16x8, b[j]),
              acc[i][j], 0, 0, 0);
    }
    __syncthreads();   // drains vmcnt(0): prefetched tile landed; cur consumed
    cur ^= 1;
  }
  #undef STAGE

  // Epilogue: E=exp(20*dot); weight 1 (same class), 1/15 (other), 0 (diag elt).
  // Row sums -> den[row]; for off-diag tiles also col sums -> den[col].
  const int rbase = row0 + wr * 64;
  const int cbase = col0 + wc * 64;
  float cs[4] = {0.f, 0.f, 0.f, 0.f};   // col partials, indexed by fj
  #pragma unroll
  for (int fi = 0; fi < 4; ++fi) {
    const int rg0 = rbase + fi * 16 + ((l >> 4) << 2);
    int labr[4];
    *(int4*)labr = *(const int4*)&label[rg0];
    float rs[4] = {0.f, 0.f, 0.f, 0.f};
    #pragma unroll
    for (int fj = 0; fj < 4; ++fj) {
      const int cg = cbase + fj * 16 + (l & 15);
      const int labc = label[cg];
      #pragma unroll
      for (int r = 0; r < 4; ++r) {
        const float e = __expf(acc[fi][fj][r] * T2INV);
        float wgt = (labr[r] == labc) ? 1.0f : (1.0f / 15.0f);
        if (rg0 + r == cg) wgt = 0.0f;   // only possible when diagTile
        const float ew = e * wgt;
        rs[r] += ew;
        cs[fj] += ew;
      }
    }
    #pragma unroll
    for (int r = 0; r < 4; ++r) {
      rs[r] += __shfl_xor(rs[r], 1);
      rs[r] += __shfl_xor(rs[r], 2);
      rs[r] += __shfl_xor(rs[r], 4);
      rs[r] += __shfl_xor(rs[r], 8);
    }
    if ((l & 15) == 0) {
      #pragma unroll
      for (int r = 0; r < 4; ++r) atomicAdd(&den[rg0 + r], rs[r]);
    }
  }
  if (!diagTile) {
    #pragma unroll
    for (int fj = 0; fj < 4; ++fj) {
      cs[fj] += __shfl_xor(cs[fj], 16);
      cs[fj] += __shfl_xor(cs[fj], 32);
    }
    if (l < 16) {
      #pragma unroll
      for (int fj = 0; fj < 4; ++fj)
        atomicAdd(&den[cbase + fj * 16 + l], cs[fj]);
    }
  }
}

__global__ __launch_bounds__(1024) void finalize_kernel(const float* __restrict__ den,
                                                        const int* __restrict__ label,
                                                        const int* __restrict__ counts,
                                                        float* __restrict__ out) {
  float s = 0.f;
  for (int i = threadIdx.x; i < 2 * NROWS; i += 1024) {
    const float d = den[i];
    const float ic = 1.0f / (float)counts[label[i & (NROWS - 1)]];
    s += log1pf(EPSV / d) * ic;
  }
  #pragma unroll
  for (int off = 32; off; off >>= 1) s += __shfl_xor(s, off);
  __shared__ float partial[16];
  if ((threadIdx.x & 63) == 0) partial[threadIdx.x >> 6] = s;
  __syncthreads();
  if (threadIdx.x == 0) {
    float tot = 0.f;
    #pragma unroll
    for (int i = 0; i < 16; ++i) tot += partial[i];
    out[0] = tot;
  }
}

extern "C" void kernel_launch(void* const* d_in, const int* in_sizes, int n_in,
                              void* d_out, int out_size, void* d_ws, size_t ws_size,
                              hipStream_t stream) {
  (void)in_sizes; (void)n_in; (void)out_size; (void)ws_size;
  const float* text  = (const float*)d_in[0];
  const float* image = (const float*)d_in[1];
  const int* label   = (const int*)d_in[2];
  const int* counts  = (const int*)d_in[3];

  ushort* Fn = (ushort*)d_ws;                                   // 2*N*D bf16
  float* den = (float*)((char*)d_ws + (size_t)2 * NROWS * DDIM * 2);  // 2*N f32

  hipMemsetAsync(den, 0, (size_t)2 * NROWS * sizeof(float), stream);
  norm_kernel<<<dim3((2 * NROWS) / 4), 256, 0, stream>>>(text, image, Fn);
  gram_kernel<<<dim3(NBLK), 256, 0, stream>>>(Fn, label, den);
  finalize_kernel<<<1, 1024, 0, stream>>>(den, label, counts, (float*)d_out);
}

// Round 4
// 152.187 us; speedup vs baseline: 1.3236x; 1.3236x over previous
//
#include <hip/hip_runtime.h>
#include <stdint.h>

#define NROWS 8192
#define DDIM 512
#define NCLS 16
#define T2INV 20.0f
#define EPSV 1e-5f
#define NTILE 64                          // NROWS / 128
#define NTRI (NTILE * (NTILE + 1) / 2)    // 2080 upper-tri tiles
#define NBLK (NTRI * 2)                   // 4160 (both matrices)

typedef __bf16 bf16x8 __attribute__((ext_vector_type(8)));
typedef short short8 __attribute__((ext_vector_type(8)));
typedef float f32x4 __attribute__((ext_vector_type(4)));

__device__ __forceinline__ ushort f2bf(float f) {
  uint32_t b = __float_as_uint(f);
  b += 0x7FFF + ((b >> 16) & 1);  // round-to-nearest-even
  return (ushort)(b >> 16);
}

// async global->LDS, 16B per lane; lds must be wave-uniform base, g per-lane.
__device__ __forceinline__ void async16(void* lds, const void* g) {
  auto gp = (__attribute__((address_space(1))) uint32_t*)(uintptr_t)g;
  auto lp = (__attribute__((address_space(3))) uint32_t*)(uintptr_t)lds;
  __builtin_amdgcn_global_load_lds(gp, lp, 16, 0, 0);
}

// Row-normalize both matrices, emit bf16, one wave per row.
__global__ __launch_bounds__(256) void norm_kernel(const float* __restrict__ text,
                                                   const float* __restrict__ image,
                                                   ushort* __restrict__ out) {
  const int w = threadIdx.x >> 6, l = threadIdx.x & 63;
  const int rid = blockIdx.x * 4 + w;            // 0 .. 2*NROWS-1
  const int m = rid >> 13;
  const int row = rid & (NROWS - 1);
  const float* src = (m ? image : text) + (size_t)row * DDIM;
  float4 v0 = ((const float4*)src)[l];
  float4 v1 = ((const float4*)src)[64 + l];
  float s = v0.x * v0.x + v0.y * v0.y + v0.z * v0.z + v0.w * v0.w +
            v1.x * v1.x + v1.y * v1.y + v1.z * v1.z + v1.w * v1.w;
  #pragma unroll
  for (int off = 32; off; off >>= 1) s += __shfl_xor(s, off);
  const float inv = 1.0f / fmaxf(sqrtf(s), 1e-12f);
  ushort4 o0, o1;
  o0.x = f2bf(v0.x * inv); o0.y = f2bf(v0.y * inv);
  o0.z = f2bf(v0.z * inv); o0.w = f2bf(v0.w * inv);
  o1.x = f2bf(v1.x * inv); o1.y = f2bf(v1.y * inv);
  o1.z = f2bf(v1.z * inv); o1.w = f2bf(v1.w * inv);
  ushort* drow = out + (size_t)rid * DDIM;
  ((ushort4*)drow)[l] = o0;
  ((ushort4*)drow)[64 + l] = o1;
}

// 128x128 bf16 MFMA Gram tile over the upper triangle (bi<=bj).
// 3-buffer LDS pipeline, BK=32, ONE raw s_barrier per K-step with COUNTED
// s_waitcnt vmcnt(4): the prefetched tile's 4 global_load_lds stay in flight
// across the barrier (T3/T4 minimum 2-phase). lgkmcnt(0) before each barrier
// closes the ds_read-completion window (rule #18 discipline).
// LDS per 16-row chunk: 16B-slot (row, s) holds global k-slot s ^ ((row>>1)&3)
// — swizzle on the GLOBAL source (global_load_lds writes linearly) and the
// same XOR on the ds_read address.
__global__ __launch_bounds__(256) void gram_kernel(const ushort* __restrict__ Fall,
                                                   const int* __restrict__ label,
                                                   float* __restrict__ denAll) {
  // XCD-chunked bijective swizzle: 4160 % 8 == 0, chunk = 520 per XCD.
  const int bid = blockIdx.x;
  const int bs = (bid & 7) * (NBLK / 8) + (bid >> 3);
  const int mat = bs >= NTRI;
  const int t = mat ? bs - NTRI : bs;
  const ushort* F = Fall + (size_t)mat * NROWS * DDIM;
  float* den = denAll + (size_t)mat * NROWS;

  // decode triangular tile id -> (q=row tile, p=col tile), q <= p
  int p = (int)((sqrtf(8.0f * (float)t + 1.0f) - 1.0f) * 0.5f);
  while ((p + 1) * (p + 2) / 2 <= t) ++p;
  while (p * (p + 1) / 2 > t) --p;
  const int q = t - p * (p + 1) / 2;
  const int row0 = q * 128, col0 = p * 128;
  const bool diagTile = (q == p);

  const int w = threadIdx.x >> 6, l = threadIdx.x & 63;
  const int wr = w >> 1, wc = w & 1;

  __shared__ ushort Alds[3][128 * 32];   // 3 bufs x 8 KB
  __shared__ ushort Blds[3][128 * 32];

  f32x4 acc[4][4] = {};

  const int lr = l >> 2;                                    // row within chunk
  const int lk = (((l & 3) ^ ((l >> 3) & 3)) * 8);          // swizzled fetch slot
  const int rdk = (((l >> 4) ^ (((l & 15) >> 1) & 3)) * 8); // swizzled read slot

  const ushort* gA = F + (size_t)row0 * DDIM + lk;
  const ushort* gB = F + (size_t)col0 * DDIM + lk;

  // stage one BK=32 tile (A+B) into buffer `buf` from k-offset k0: 4 loads/wave
  #define STAGE(buf, k0)                                                      \
    {                                                                         \
      _Pragma("unroll")                                                       \
      for (int c = 0; c < 2; ++c) {                                           \
        const int chunk = w * 2 + c;                                          \
        const int r = chunk * 16 + lr;                                        \
        async16(&Alds[buf][chunk * 512], gA + (size_t)r * DDIM + (k0));       \
        async16(&Blds[buf][chunk * 512], gB + (size_t)r * DDIM + (k0));       \
      }                                                                       \
    }

  #define COMPUTE(buf)                                                        \
    {                                                                         \
      short8 a[4], b[4];                                                      \
      _Pragma("unroll")                                                       \
      for (int f = 0; f < 4; ++f) {                                           \
        a[f] = *(const short8*)&Alds[buf][(wr * 64 + f * 16 + (l & 15)) * 32 + rdk]; \
        b[f] = *(const short8*)&Blds[buf][(wc * 64 + f * 16 + (l & 15)) * 32 + rdk]; \
      }                                                                       \
      _Pragma("unroll")                                                       \
      for (int i = 0; i < 4; ++i) {                                           \
        _Pragma("unroll")                                                     \
        for (int j = 0; j < 4; ++j)                                           \
          acc[i][j] = __builtin_amdgcn_mfma_f32_16x16x32_bf16(                \
              __builtin_bit_cast(bf16x8, a[i]), __builtin_bit_cast(bf16x8, b[j]), \
              acc[i][j], 0, 0, 0);                                            \
      }                                                                       \
    }

  STAGE(0, 0);
  int cur = 0, nxt = 1;
  for (int ks = 0; ks < DDIM / 32 - 1; ++ks) {
    STAGE(nxt, (ks + 1) * 32);
    // tile `cur`'s 4 loads (issued last iter) drained; tile `nxt`'s 4 in flight
    asm volatile("s_waitcnt vmcnt(4) lgkmcnt(0)" ::: "memory");
    __builtin_amdgcn_s_barrier();
    COMPUTE(cur);
    cur = nxt;
    nxt = (nxt == 2) ? 0 : nxt + 1;
  }
  asm volatile("s_waitcnt vmcnt(0) lgkmcnt(0)" ::: "memory");
  __builtin_amdgcn_s_barrier();
  COMPUTE(cur);
  #undef STAGE
  #undef COMPUTE

  // Epilogue: E=exp(20*dot); weight 1 (same class), 1/15 (other), 0 (diag elt).
  // Row sums -> den[row]; for off-diag tiles also col sums -> den[col].
  const int rbase = row0 + wr * 64;
  const int cbase = col0 + wc * 64;
  float cs[4] = {0.f, 0.f, 0.f, 0.f};   // col partials, indexed by fj
  #pragma unroll
  for (int fi = 0; fi < 4; ++fi) {
    const int rg0 = rbase + fi * 16 + ((l >> 4) << 2);
    int labr[4];
    *(int4*)labr = *(const int4*)&label[rg0];
    float rs[4] = {0.f, 0.f, 0.f, 0.f};
    #pragma unroll
    for (int fj = 0; fj < 4; ++fj) {
      const int cg = cbase + fj * 16 + (l & 15);
      const int labc = label[cg];
      #pragma unroll
      for (int r = 0; r < 4; ++r) {
        const float e = __expf(acc[fi][fj][r] * T2INV);
        float wgt = (labr[r] == labc) ? 1.0f : (1.0f / 15.0f);
        if (rg0 + r == cg) wgt = 0.0f;   // only possible when diagTile
        const float ew = e * wgt;
        rs[r] += ew;
        cs[fj] += ew;
      }
    }
    #pragma unroll
    for (int r = 0; r < 4; ++r) {
      rs[r] += __shfl_xor(rs[r], 1);
      rs[r] += __shfl_xor(rs[r], 2);
      rs[r] += __shfl_xor(rs[r], 4);
      rs[r] += __shfl_xor(rs[r], 8);
    }
    if ((l & 15) == 0) {
      #pragma unroll
      for (int r = 0; r < 4; ++r) atomicAdd(&den[rg0 + r], rs[r]);
    }
  }
  if (!diagTile) {
    #pragma unroll
    for (int fj = 0; fj < 4; ++fj) {
      cs[fj] += __shfl_xor(cs[fj], 16);
      cs[fj] += __shfl_xor(cs[fj], 32);
    }
    if (l < 16) {
      #pragma unroll
      for (int fj = 0; fj < 4; ++fj)
        atomicAdd(&den[cbase + fj * 16 + l], cs[fj]);
    }
  }
}

__global__ __launch_bounds__(1024) void finalize_kernel(const float* __restrict__ den,
                                                        const int* __restrict__ label,
                                                        const int* __restrict__ counts,
                                                        float* __restrict__ out) {
  float s = 0.f;
  for (int i = threadIdx.x; i < 2 * NROWS; i += 1024) {
    const float d = den[i];
    const float ic = 1.0f / (float)counts[label[i & (NROWS - 1)]];
    s += log1pf(EPSV / d) * ic;
  }
  #pragma unroll
  for (int off = 32; off; off >>= 1) s += __shfl_xor(s, off);
  __shared__ float partial[16];
  if ((threadIdx.x & 63) == 0) partial[threadIdx.x >> 6] = s;
  __syncthreads();
  if (threadIdx.x == 0) {
    float tot = 0.f;
    #pragma unroll
    for (int i = 0; i < 16; ++i) tot += partial[i];
    out[0] = tot;
  }
}

extern "C" void kernel_launch(void* const* d_in, const int* in_sizes, int n_in,
                              void* d_out, int out_size, void* d_ws, size_t ws_size,
                              hipStream_t stream) {
  (void)in_sizes; (void)n_in; (void)out_size; (void)ws_size;
  const float* text  = (const float*)d_in[0];
  const float* image = (const float*)d_in[1];
  const int* label   = (const int*)d_in[2];
  const int* counts  = (const int*)d_in[3];

  ushort* Fn = (ushort*)d_ws;                                   // 2*N*D bf16
  float* den = (float*)((char*)d_ws + (size_t)2 * NROWS * DDIM * 2);  // 2*N f32

  hipMemsetAsync(den, 0, (size_t)2 * NROWS * sizeof(float), stream);
  norm_kernel<<<dim3((2 * NROWS) / 4), 256, 0, stream>>>(text, image, Fn);
  gram_kernel<<<dim3(NBLK), 256, 0, stream>>>(Fn, label, den);
  finalize_kernel<<<1, 1024, 0, stream>>>(den, label, counts, (float*)d_out);
}